// Round 17
// baseline (131.802 us; speedup 1.0000x reference)
//
#include <hip/hip_runtime.h>
#include <math.h>

#define NBATCH 16
#define NN 63
#define XS 68   // XK/XKT row stride in words: 16B-aligned rows, 272B = 17*16B (odd group step)

typedef __attribute__((ext_vector_type(8))) short short8;
typedef __attribute__((ext_vector_type(4))) float f32x4;

__device__ __forceinline__ unsigned short f2bf(float f) {
    unsigned int u = __float_as_uint(f);
    u += 0x7fffu + ((u >> 16) & 1u);   // RNE
    return (unsigned short)(u >> 16);
}

template <int CTRL>
__device__ __forceinline__ float dpp_add(float s) {
    int si = __builtin_bit_cast(int, s);
    int t  = __builtin_amdgcn_update_dpp(si, si, CTRL, 0xF, 0xF, true);
    return s + __builtin_bit_cast(float, t);
}
// sum over each aligned 8-lane group (xor1, xor2, xor7)
__device__ __forceinline__ float red8_dpp(float s) {
    s = dpp_add<0xB1>(s);    // quad_perm [1,0,3,2]
    s = dpp_add<0x4E>(s);    // quad_perm [2,3,0,1]
    s = dpp_add<0x141>(s);   // row_half_mirror
    return s;
}

// One block per batch element. 512 threads = 8 waves.
// __launch_bounds__(512, 1): hipcc uses CUDA semantics for arg2 (min BLOCKS
// per CU — measured R16: arg=2 -> 16 waves/CU -> VGPR cap 128, spills).
// arg=1 -> 8 waves/CU = 2 waves/SIMD -> VGPR cap 256; wave-0 sinkhorn needs
// ~216 (88 base + 128 for Kr[16]+Kc[16] f32x4) -> no spill.
// Tile/slot mapping: wave w owns tiles t = w, w+8; (rt,ct) = (t>>2, t&3);
// slot (s,r): i = rt*16 + (lane>>4)*4 + r, j = ct*16 + (lane&15) = MFMA D-frag.
// Sinkhorn: WAVE 0 ONLY, register-resident K rows (Kr) + cols (Kc via XKT);
// u/v broadcast through 64-float LDS vectors; no barriers inside.
__global__ __launch_bounds__(512, 1) void ged_kernel(
    const float* __restrict__ node_w, const float* __restrict__ edge_w,
    const int* __restrict__ A1g, const int* __restrict__ A2g,
    const int* __restrict__ l1g, const int* __restrict__ l2g,
    float* __restrict__ ged_out)
{
    const int b    = blockIdx.x;
    const int tid  = threadIdx.x;
    const int lane = tid & 63;
    const int w    = tid >> 6;        // 0..7
    const int lr   = lane & 15;
    const int lg   = lane >> 4;

    __shared__ __align__(16) float XK[64*XS];              // K then X, [row*XS+col]
    __shared__ __align__(16) float XKT[64*XS];             // K^T, [col*XS+row]
    __shared__ __align__(16) unsigned short Xb[4096];      // X bf16, frag-major
    __shared__ __align__(16) unsigned short Rb[4][4096];   // R'_a^T, frag-major
    __shared__ __align__(16) unsigned short Wb[4][4096];   // W_a (symmetric)
    __shared__ __align__(16) unsigned short I1b[4][4096];  // I1_a (symmetric)
    __shared__ __align__(16) float rX[64];                 // rowsum(X)
    __shared__ __align__(16) float us[64];
    __shared__ __align__(16) float vs[64];
    __shared__ __align__(16) float red[16];
    __shared__ float ncost[64];
    __shared__ unsigned short Qbf[20];                     // [a*5 + v], v=0 -> 0
    __shared__ float cns[29], ces[7];
    __shared__ float deg2f[64];
    __shared__ int l1s[64], l2s[64];

    // ---- phase A: weights + labels ----
    if (tid < 29) cns[tid] = fmaxf(node_w[tid], 0.f);
    else if (tid >= 32 && tid < 39) ces[tid-32] = fmaxf(edge_w[tid-32], 0.f);
    if (tid >= 64 && tid < 128) l1s[tid-64] = (tid-64 < NN) ? l1g[b*NN + tid-64] : 0;
    else if (tid >= 128 && tid < 192) l2s[tid-128] = (tid-128 < NN) ? l2g[b*NN + tid-128] : 0;
    __syncthreads();
    // ---- phase B: cost tables ----
    if (tid < 64) {
        int r0 = tid >> 3, c1 = tid & 7;
        float vv = 0.f;
        if (r0 != c1) {
            int lo = min(r0, c1), hi = max(r0, c1);
            vv = cns[lo*7 - (lo*(lo-1))/2 + (hi-lo-1)];
        }
        ncost[tid] = vv;
    } else if (tid < 80) {
        int a = (tid-64) >> 2, b2 = tid & 3;
        float ec = 0.f;
        if (a != b2) {
            int lo = min(a, b2), hi = max(a, b2);
            ec = ces[lo*3 - (lo*(lo-1))/2 + (hi-lo-1)];
        }
        Qbf[a*5 + b2 + 1] = f2bf(2.f*ec - 2.f*ces[6]);
    } else if (tid < 84) {
        Qbf[(tid-80)*5] = 0;
    }
    __syncthreads();
    // ---- phase C: build W/I1 planes (frag-major scatter) + deg2 ----
    #pragma unroll
    for (int r = 0; r < 8; ++r) {
        int row = w + (r << 3);          // wave-uniform, covers 0..63
        int v2 = 0, v1 = 0;
        if (row < NN && lane < NN) {
            v2 = A2g[((size_t)b*NN + row)*NN + lane];
            v1 = A1g[((size_t)b*NN + row)*NN + lane];
        }
        int T = row >> 4, lrr = row & 15;
        int kc = lane >> 5, lgg = (lane >> 3) & 3, e = lane & 7;
        int ci = ((((T<<1)+kc)*4 + lgg)*16 + lrr)*8 + e;
        Wb[0][ci] = Qbf[ 0 + v2];
        Wb[1][ci] = Qbf[ 5 + v2];
        Wb[2][ci] = Qbf[10 + v2];
        Wb[3][ci] = Qbf[15 + v2];
        unsigned long long mv = __ballot(v2 != 0);
        if (lane == 0) deg2f[row] = (float)__popcll(mv);
        I1b[0][ci] = (v1 == 1) ? 0x3F80 : 0;
        I1b[1][ci] = (v1 == 2) ? 0x3F80 : 0;
        I1b[2][ci] = (v1 == 3) ? 0x3F80 : 0;
        I1b[3][ci] = (v1 == 4) ? 0x3F80 : 0;
    }
    __syncthreads();

    const float eid = ces[6];
    const float nid = cns[28];

    // ---- slot geometry ----
    int i0s[2], jcs[2], rts[2], cts[2];
    float ed2s[2];
    #pragma unroll
    for (int s = 0; s < 2; ++s) {
        int t = w + (s << 3);
        rts[s] = t >> 2; cts[s] = t & 3;
        i0s[s] = rts[s]*16 + lg*4;
        jcs[s] = cts[s]*16 + lr;
        ed2s[s] = eid * deg2f[jcs[s]];
    }

    float c_reg[2][4];
    #pragma unroll
    for (int s = 0; s < 2; ++s)
        #pragma unroll
        for (int r = 0; r < 4; ++r) {
            int i = i0s[s] + r, j = jcs[s];
            c_reg[s][r] = (i < NN && j < NN) ? ncost[(l1s[i] << 3) + l2s[j]]
                          : ((i == NN && j == NN) ? 0.f : nid);
        }

    const int q8  = tid & 7;
    const int rr8 = tid >> 3;     // 0..63
    const int c8  = q8 << 3;

    // K = exp(-g), written to XK and XKT (both needed by wave-0 sinkhorn)
    auto expK = [&](float (*gv)[4]) {
        #pragma unroll
        for (int s = 0; s < 2; ++s)
            #pragma unroll
            for (int r = 0; r < 4; ++r) {
                float e = __expf(-gv[s][r]);
                XK [(i0s[s] + r)*XS + jcs[s]] = e;
                XKT[jcs[s]*XS + (i0s[s] + r)] = e;
            }
        __syncthreads();
    };

    // wave-0 register-resident sinkhorn: u0 = 1/rowsum, then v = 1/(K^T u),
    // u = 1/(K v). u/v broadcast via LDS; no barriers (single-wave lockstep).
    auto sinkW0 = [&](int iters) {
        if (w == 0) {
            f32x4 Kr[16], Kc[16];
            #pragma unroll
            for (int u = 0; u < 16; ++u) {
                Kr[u] = *(const f32x4*)&XK [lane*XS + (u << 2)];
                Kc[u] = *(const f32x4*)&XKT[lane*XS + (u << 2)];
            }
            float s0 = 0.f;
            #pragma unroll
            for (int u = 0; u < 16; ++u)
                s0 += (Kr[u][0] + Kr[u][1]) + (Kr[u][2] + Kr[u][3]);
            us[lane] = (lane < NN) ? __builtin_amdgcn_rcpf(s0) : 1.f;
            for (int it = 0; it < iters; ++it) {
                float t = 0.f;
                #pragma unroll
                for (int u = 0; u < 16; ++u) {
                    f32x4 uu = *(const f32x4*)&us[u << 2];
                    t += (Kc[u][0]*uu[0] + Kc[u][1]*uu[1])
                       + (Kc[u][2]*uu[2] + Kc[u][3]*uu[3]);
                }
                vs[lane] = (lane < NN) ? __builtin_amdgcn_rcpf(t) : 1.f;
                if (it + 1 < iters) {
                    float t2 = 0.f;
                    #pragma unroll
                    for (int u = 0; u < 16; ++u) {
                        f32x4 vv = *(const f32x4*)&vs[u << 2];
                        t2 += (Kr[u][0]*vv[0] + Kr[u][1]*vv[1])
                            + (Kr[u][2]*vv[2] + Kr[u][3]*vv[3]);
                    }
                    us[lane] = (lane < NN) ? __builtin_amdgcn_rcpf(t2) : 1.f;
                }
            }
        }
        __syncthreads();
    };

    // all-thread finalize: X = u*K*v into XK (b128) + Xb (bf16 frag) + rX
    auto fin8all = [&]() {
        f32x4 k0 = *(const f32x4*)&XK[rr8*XS + c8];
        f32x4 k1 = *(const f32x4*)&XK[rr8*XS + c8 + 4];
        f32x4 va = *(const f32x4*)&vs[c8];
        f32x4 vb = *(const f32x4*)&vs[c8 + 4];
        float uR = us[rr8];
        float p0 = k0[0]*va[0], p1 = k0[1]*va[1], p2 = k0[2]*va[2], p3 = k0[3]*va[3];
        float p4 = k1[0]*vb[0], p5 = k1[1]*vb[1], p6 = k1[2]*vb[2], p7 = k1[3]*vb[3];
        float sr = red8_dpp(((p0+p1)+(p2+p3)) + ((p4+p5)+(p6+p7)));
        f32x4 xa = {uR*p0, uR*p1, uR*p2, uR*p3};
        f32x4 xb2 = {uR*p4, uR*p5, uR*p6, uR*p7};
        *(f32x4*)&XK[rr8*XS + c8]     = xa;
        *(f32x4*)&XK[rr8*XS + c8 + 4] = xb2;
        short8 xs;
        xs[0] = (short)f2bf(xa[0]); xs[1] = (short)f2bf(xa[1]);
        xs[2] = (short)f2bf(xa[2]); xs[3] = (short)f2bf(xa[3]);
        xs[4] = (short)f2bf(xb2[0]); xs[5] = (short)f2bf(xb2[1]);
        xs[6] = (short)f2bf(xb2[2]); xs[7] = (short)f2bf(xb2[3]);
        int ci = (((((rr8>>4)<<1) + (q8>>2))*4 + (q8&3))*16 + (rr8&15)) << 3;
        *(short8*)&Xb[ci] = xs;
        if (q8 == 0) rX[rr8] = uR * sr;
        __syncthreads();
    };

    // M1: P_a = X * W_a (MFMA) + eid*rX fold, write R'_a^T bf16 into Rb
    auto M1R = [&]() {
        #pragma unroll
        for (int s = 0; s < 2; ++s) {
            const int rt = rts[s], ct = cts[s];
            f32x4 P0 = {0.f,0.f,0.f,0.f}, P1 = P0, P2 = P0, P3 = P0;
            #pragma unroll
            for (int kc = 0; kc < 2; ++kc) {
                const int ai = ((((rt<<1)+kc)*4 + lg)*16 + lr) << 3;
                const int bi = ((((ct<<1)+kc)*4 + lg)*16 + lr) << 3;
                short8 af = *(const short8*)&Xb[ai];
                P0 = __builtin_amdgcn_mfma_f32_16x16x32_bf16(af, *(const short8*)&Wb[0][bi], P0, 0,0,0);
                P1 = __builtin_amdgcn_mfma_f32_16x16x32_bf16(af, *(const short8*)&Wb[1][bi], P1, 0,0,0);
                P2 = __builtin_amdgcn_mfma_f32_16x16x32_bf16(af, *(const short8*)&Wb[2][bi], P2, 0,0,0);
                P3 = __builtin_amdgcn_mfma_f32_16x16x32_bf16(af, *(const short8*)&Wb[3][bi], P3, 0,0,0);
            }
            f32x4 rx4 = *(const f32x4*)&rX[i0s[s]];
            P0[0] += eid*rx4[0]; P0[1] += eid*rx4[1]; P0[2] += eid*rx4[2]; P0[3] += eid*rx4[3];
            P1[0] += eid*rx4[0]; P1[1] += eid*rx4[1]; P1[2] += eid*rx4[2]; P1[3] += eid*rx4[3];
            P2[0] += eid*rx4[0]; P2[1] += eid*rx4[1]; P2[2] += eid*rx4[2]; P2[3] += eid*rx4[3];
            P3[0] += eid*rx4[0]; P3[1] += eid*rx4[1]; P3[2] += eid*rx4[2]; P3[3] += eid*rx4[3];
            const int cw = (((ct<<1) + (rt>>1))*4 + ((rt&1)*2 + (lg>>1)))*16 + lr;
            const int si = (cw << 3) + ((lg & 1) << 2);
            {
                unsigned long long v =  (unsigned long long)(f2bf(P0[0]) | ((unsigned)f2bf(P0[1])<<16))
                                     | ((unsigned long long)(f2bf(P0[2]) | ((unsigned)f2bf(P0[3])<<16)) << 32);
                *(unsigned long long*)&Rb[0][si] = v;
            }
            {
                unsigned long long v =  (unsigned long long)(f2bf(P1[0]) | ((unsigned)f2bf(P1[1])<<16))
                                     | ((unsigned long long)(f2bf(P1[2]) | ((unsigned)f2bf(P1[3])<<16)) << 32);
                *(unsigned long long*)&Rb[1][si] = v;
            }
            {
                unsigned long long v =  (unsigned long long)(f2bf(P2[0]) | ((unsigned)f2bf(P2[1])<<16))
                                     | ((unsigned long long)(f2bf(P2[2]) | ((unsigned)f2bf(P2[3])<<16)) << 32);
                *(unsigned long long*)&Rb[2][si] = v;
            }
            {
                unsigned long long v =  (unsigned long long)(f2bf(P3[0]) | ((unsigned)f2bf(P3[1])<<16))
                                     | ((unsigned long long)(f2bf(P3[2]) | ((unsigned)f2bf(P3[3])<<16)) << 32);
                *(unsigned long long*)&Rb[3][si] = v;
            }
        }
        __syncthreads();
    };

    // M2: out = sum_a I1_a * R'_a  (+ eid*deg2), db in D-frag regs
    auto M2 = [&](float (*out)[4]) {
        #pragma unroll
        for (int s = 0; s < 2; ++s) {
            const int rt = rts[s], ct = cts[s];
            f32x4 acc = {0.f,0.f,0.f,0.f};
            #pragma unroll
            for (int kc = 0; kc < 2; ++kc) {
                const int ai = ((((rt<<1)+kc)*4 + lg)*16 + lr) << 3;
                const int bi = ((((ct<<1)+kc)*4 + lg)*16 + lr) << 3;
                #pragma unroll
                for (int a = 0; a < 4; ++a) {
                    short8 af = *(const short8*)&I1b[a][ai];
                    short8 bf = *(const short8*)&Rb[a][bi];
                    acc = __builtin_amdgcn_mfma_f32_16x16x32_bf16(af, bf, acc, 0,0,0);
                }
            }
            #pragma unroll
            for (int r = 0; r < 4; ++r) out[s][r] = acc[r] + ed2s[s];
        }
    };

    // ---- init: x0 = sinkhorn(exp(-c), 10); dx = D @ x0 ----
    expK(c_reg);
    sinkW0(10);
    fin8all();
    M1R();
    float x[2][4], dx[2][4], bb[2][4], gvv[2][4];
    M2(dx);
    #pragma unroll
    for (int s = 0; s < 2; ++s)
        #pragma unroll
        for (int r = 0; r < 4; ++r)
            x[s][r] = XK[(i0s[s] + r)*XS + jcs[s]];

    // ---- Frank-Wolfe iterations ----
    for (int it = 0; it < 15; ++it) {
        #pragma unroll
        for (int s = 0; s < 2; ++s)
            #pragma unroll
            for (int r = 0; r < 4; ++r)
                gvv[s][r] = c_reg[s][r] + dx[s][r];
        expK(gvv);
        sinkW0(5);
        fin8all();
        M1R();
        float db[2][4];
        M2(db);
        #pragma unroll
        for (int s = 0; s < 2; ++s)
            #pragma unroll
            for (int r = 0; r < 4; ++r)
                bb[s][r] = XK[(i0s[s] + r)*XS + jcs[s]];
        float dn = 0.f, nm = 0.f;
        #pragma unroll
        for (int s = 0; s < 2; ++s)
            #pragma unroll
            for (int r = 0; r < 4; ++r) {
                float d = bb[s][r] - x[s][r];
                dn += d * (db[s][r] - dx[s][r]);
                nm += d * gvv[s][r];
            }
        dn = red8_dpp(dn);  nm = red8_dpp(nm);
        dn += __shfl_xor(dn, 8, 64);  nm += __shfl_xor(nm, 8, 64);
        dn += __shfl_xor(dn, 16, 64); nm += __shfl_xor(nm, 16, 64);
        dn += __shfl_xor(dn, 32, 64); nm += __shfl_xor(nm, 32, 64);
        if (lane == 0) { red[w] = dn; red[8 + w] = nm; }
        __syncthreads();
        f32x4 pa = *(const f32x4*)&red[0], pb = *(const f32x4*)&red[4];
        f32x4 pc = *(const f32x4*)&red[8], pd = *(const f32x4*)&red[12];
        float den = (pa[0]+pa[1]+pa[2]+pa[3]) + (pb[0]+pb[1]+pb[2]+pb[3]);
        float num = (pc[0]+pc[1]+pc[2]+pc[3]) + (pd[0]+pd[1]+pd[2]+pd[3]);
        float t;
        if (den > 0.f) t = fminf(fmaxf(-num / den, 0.f), 1.f);
        else           t = (num < 0.f) ? 1.f : 0.f;
        #pragma unroll
        for (int s = 0; s < 2; ++s)
            #pragma unroll
            for (int r = 0; r < 4; ++r) {
                float d = bb[s][r] - x[s][r];
                x[s][r]  += t * d;
                dx[s][r] += t * (db[s][r] - dx[s][r]);   // D x_new by linearity
            }
    }

    // ---- ged = 0.5 * x.Dx + c.x ----
    __syncthreads();   // red[] reads above complete before rewrite
    float g2 = 0.f;
    #pragma unroll
    for (int s = 0; s < 2; ++s)
        #pragma unroll
        for (int r = 0; r < 4; ++r)
            g2 += x[s][r] * (0.5f * dx[s][r] + c_reg[s][r]);
    g2 = red8_dpp(g2);
    g2 += __shfl_xor(g2, 8, 64);
    g2 += __shfl_xor(g2, 16, 64);
    g2 += __shfl_xor(g2, 32, 64);
    if (lane == 0) red[w] = g2;
    __syncthreads();
    if (tid == 0) {
        float s = 0.f;
        #pragma unroll
        for (int u = 0; u < 8; ++u) s += red[u];
        ged_out[b] = s;
    }
}

__global__ void norm_kernel(const float* __restrict__ g, float* __restrict__ out) {
    int t = threadIdx.x;
    if (t < NBATCH) {
        float mn = g[0], mx = g[0];
        #pragma unroll
        for (int i = 1; i < NBATCH; ++i) { mn = fminf(mn, g[i]); mx = fmaxf(mx, g[i]); }
        out[t] = (g[t] - mn) / (mx - mn);
    }
}

extern "C" void kernel_launch(void* const* d_in, const int* in_sizes, int n_in,
                              void* d_out, int out_size, void* d_ws, size_t ws_size,
                              hipStream_t stream) {
    (void)in_sizes; (void)n_in; (void)out_size; (void)ws_size;
    const float* node_w = (const float*)d_in[0];
    const float* edge_w = (const float*)d_in[1];
    const int*   A1     = (const int*)d_in[2];
    const int*   A2     = (const int*)d_in[3];
    const int*   l1     = (const int*)d_in[4];
    const int*   l2     = (const int*)d_in[5];
    float* ged = (float*)d_ws;
    ged_kernel<<<dim3(NBATCH), dim3(512), 0, stream>>>(node_w, edge_w, A1, A2, l1, l2, ged);
    norm_kernel<<<dim3(1), dim3(64), 0, stream>>>(ged, (float*)d_out);
}

// Round 18
// 80.173 us; speedup vs baseline: 1.6440x; 1.6440x over previous
//
#include <hip/hip_runtime.h>
#include <math.h>

#define NBATCH 16
#define NN 63

typedef __attribute__((ext_vector_type(8))) short short8;
typedef __attribute__((ext_vector_type(4))) float f32x4;

__device__ __forceinline__ unsigned short f2bf(float f) {
    unsigned int u = __float_as_uint(f);
    u += 0x7fffu + ((u >> 16) & 1u);   // RNE
    return (unsigned short)(u >> 16);
}

// DPP add: s + dpp_move(s, CTRL) — VALU only, no DS-pipe traffic.
// CTRL must be a compile-time constant (template parameter).
template <int CTRL>
__device__ __forceinline__ float dpp_add(float s) {
    int si = __builtin_bit_cast(int, s);
    int t  = __builtin_amdgcn_update_dpp(si, si, CTRL, 0xF, 0xF, true);
    return s + __builtin_bit_cast(float, t);
}
// sum over each aligned 8-lane group: xor1 (quad_perm), xor2 (quad_perm),
// then xor7 (row_half_mirror) which adds the other quad's quad-sum.
__device__ __forceinline__ float red8_dpp(float s) {
    s = dpp_add<0xB1>(s);    // quad_perm [1,0,3,2]  (xor 1)
    s = dpp_add<0x4E>(s);    // quad_perm [2,3,0,1]  (xor 2)
    s = dpp_add<0x141>(s);   // row_half_mirror      (xor 7)
    return s;
}

// One block per batch element. 512 threads = 8 waves.
// R18 = R13 verbatim: distributed sinkhorn (8 threads/row), VGPR 88, no spill.
// (R15-R17 wave-0 register-resident sinkhorn is infeasible: allocator caps
// arch VGPRs at 128 for this 8-wave MFMA kernel regardless of launch_bounds;
// Kr[16]+Kc[16] = 128 extra VGPRs always spills to scratch, 80 -> 131 us.)
// Tile/slot mapping: wave w owns tiles t = w, w+8; (rt,ct) = (t>>2, t&3);
// slot (s,r): i = rt*16 + (lane>>4)*4 + r, j = ct*16 + (lane&15) = MFMA D-frag.
// Sinkhorn mapping: rr8 = tid>>3 (row 0..63), q8 = tid&7, 8 elems/thread.
// bf16 planes use fragment-major chunk layout (conflict-free b128 frag reads).
// Rank-1 term eid*rX*1^T is folded into R (I1any == sum_a I1_a, labels disjoint).
__global__ __launch_bounds__(512) void ged_kernel(
    const float* __restrict__ node_w, const float* __restrict__ edge_w,
    const int* __restrict__ A1g, const int* __restrict__ A2g,
    const int* __restrict__ l1g, const int* __restrict__ l2g,
    float* __restrict__ ged_out)
{
    const int b    = blockIdx.x;
    const int tid  = threadIdx.x;
    const int lane = tid & 63;
    const int w    = tid >> 6;        // 0..7
    const int lr   = lane & 15;
    const int lg   = lane >> 4;

    __shared__ __align__(16) float XK[64*65];              // K then X, [row*65+col]
    __shared__ __align__(16) unsigned short Xb[4096];      // X bf16, frag-major
    __shared__ __align__(16) unsigned short Rb[4][4096];   // R'_a^T, frag-major
    __shared__ __align__(16) unsigned short Wb[4][4096];   // W_a, frag-major (symmetric)
    __shared__ __align__(16) unsigned short I1b[4][4096];  // I1_a, frag-major (symmetric)
    __shared__ __align__(16) float rX[64];                 // rowsum(X)
    __shared__ __align__(16) float us[64];
    __shared__ __align__(16) float vs[64];
    __shared__ __align__(16) float red[16];
    __shared__ float ncost[64];
    __shared__ unsigned short Qbf[20];                     // [a*5 + v], v=0 -> 0
    __shared__ float cns[29], ces[7];
    __shared__ float deg2f[64];
    __shared__ int l1s[64], l2s[64];

    // ---- phase A: weights + labels ----
    if (tid < 29) cns[tid] = fmaxf(node_w[tid], 0.f);
    else if (tid >= 32 && tid < 39) ces[tid-32] = fmaxf(edge_w[tid-32], 0.f);
    if (tid >= 64 && tid < 128) l1s[tid-64] = (tid-64 < NN) ? l1g[b*NN + tid-64] : 0;
    else if (tid >= 128 && tid < 192) l2s[tid-128] = (tid-128 < NN) ? l2g[b*NN + tid-128] : 0;
    __syncthreads();
    // ---- phase B: cost tables ----
    if (tid < 64) {
        int r0 = tid >> 3, c1 = tid & 7;
        float vv = 0.f;
        if (r0 != c1) {
            int lo = min(r0, c1), hi = max(r0, c1);
            vv = cns[lo*7 - (lo*(lo-1))/2 + (hi-lo-1)];
        }
        ncost[tid] = vv;
    } else if (tid < 80) {
        int a = (tid-64) >> 2, b2 = tid & 3;
        float ec = 0.f;
        if (a != b2) {
            int lo = min(a, b2), hi = max(a, b2);
            ec = ces[lo*3 - (lo*(lo-1))/2 + (hi-lo-1)];
        }
        Qbf[a*5 + b2 + 1] = f2bf(2.f*ec - 2.f*ces[6]);
    } else if (tid < 84) {
        Qbf[(tid-80)*5] = 0;
    }
    __syncthreads();
    // ---- phase C: build W/I1 planes (frag-major scatter) + deg2 ----
    #pragma unroll
    for (int r = 0; r < 8; ++r) {
        int row = w + (r << 3);          // wave-uniform, covers 0..63
        int v2 = 0, v1 = 0;
        if (row < NN && lane < NN) {
            v2 = A2g[((size_t)b*NN + row)*NN + lane];
            v1 = A1g[((size_t)b*NN + row)*NN + lane];
        }
        // frag address for element (row, col=lane):
        int T = row >> 4, lrr = row & 15;
        int kc = lane >> 5, lgg = (lane >> 3) & 3, e = lane & 7;
        int ci = ((((T<<1)+kc)*4 + lgg)*16 + lrr)*8 + e;
        Wb[0][ci] = Qbf[ 0 + v2];
        Wb[1][ci] = Qbf[ 5 + v2];
        Wb[2][ci] = Qbf[10 + v2];
        Wb[3][ci] = Qbf[15 + v2];
        unsigned long long mv = __ballot(v2 != 0);
        if (lane == 0) deg2f[row] = (float)__popcll(mv);
        I1b[0][ci] = (v1 == 1) ? 0x3F80 : 0;
        I1b[1][ci] = (v1 == 2) ? 0x3F80 : 0;
        I1b[2][ci] = (v1 == 3) ? 0x3F80 : 0;
        I1b[3][ci] = (v1 == 4) ? 0x3F80 : 0;
    }
    __syncthreads();

    const float eid = ces[6];
    const float nid = cns[28];

    // ---- slot geometry ----
    int i0s[2], jcs[2], rts[2], cts[2];
    float ed2s[2];
    #pragma unroll
    for (int s = 0; s < 2; ++s) {
        int t = w + (s << 3);
        rts[s] = t >> 2; cts[s] = t & 3;
        i0s[s] = rts[s]*16 + lg*4;
        jcs[s] = cts[s]*16 + lr;
        ed2s[s] = eid * deg2f[jcs[s]];
    }

    float c_reg[2][4];
    #pragma unroll
    for (int s = 0; s < 2; ++s)
        #pragma unroll
        for (int r = 0; r < 4; ++r) {
            int i = i0s[s] + r, j = jcs[s];
            c_reg[s][r] = (i < NN && j < NN) ? ncost[(l1s[i] << 3) + l2s[j]]
                          : ((i == NN && j == NN) ? 0.f : nid);
        }

    const int q8  = tid & 7;
    const int rr8 = tid >> 3;     // 0..63
    const int c8  = q8 << 3;
    float Krow[8], Kcol[8];

    // K = exp(-g) in D-fragment mapping
    auto expK = [&](float (*gv)[4]) {
        #pragma unroll
        for (int s = 0; s < 2; ++s)
            #pragma unroll
            for (int r = 0; r < 4; ++r)
                XK[(i0s[s] + r)*65 + jcs[s]] = __expf(-gv[s][r]);
        __syncthreads();
    };

    // scaling-vector sinkhorn: u0 = 1/rowsum, then v = 1/(u^T K), u = 1/(K v)
    auto sink8 = [&](int iters) {
        #pragma unroll
        for (int u = 0; u < 8; ++u) {
            Krow[u] = XK[rr8*65 + c8 + u];
            Kcol[u] = XK[(c8+u)*65 + rr8];
        }
        float s0 = ((Krow[0]+Krow[1])+(Krow[2]+Krow[3]))+((Krow[4]+Krow[5])+(Krow[6]+Krow[7]));
        s0 = red8_dpp(s0);
        if (q8 == 0) us[rr8] = (rr8 < NN) ? __builtin_amdgcn_rcpf(s0) : 1.f;
        __syncthreads();
        for (int it = 0; it < iters; ++it) {
            {
                float4 ua = *(const float4*)&us[c8], ub = *(const float4*)&us[c8+4];
                float t = ((Kcol[0]*ua.x + Kcol[1]*ua.y) + (Kcol[2]*ua.z + Kcol[3]*ua.w))
                        + ((Kcol[4]*ub.x + Kcol[5]*ub.y) + (Kcol[6]*ub.z + Kcol[7]*ub.w));
                t = red8_dpp(t);
                if (q8 == 0) vs[rr8] = (rr8 < NN) ? __builtin_amdgcn_rcpf(t) : 1.f;
            }
            __syncthreads();
            if (it + 1 < iters) {
                float4 va = *(const float4*)&vs[c8], vb = *(const float4*)&vs[c8+4];
                float t = ((Krow[0]*va.x + Krow[1]*va.y) + (Krow[2]*va.z + Krow[3]*va.w))
                        + ((Krow[4]*vb.x + Krow[5]*vb.y) + (Krow[6]*vb.z + Krow[7]*vb.w));
                t = red8_dpp(t);
                if (q8 == 0) us[rr8] = (rr8 < NN) ? __builtin_amdgcn_rcpf(t) : 1.f;
                __syncthreads();
            }
        }
    };

    // X = u*K*v into XK (f32) + Xb (bf16 frag chunk) + rX (f32 rowsum)
    auto fin8 = [&]() {
        float4 va = *(const float4*)&vs[c8], vb = *(const float4*)&vs[c8+4];
        float uR = us[rr8];
        float p[8];
        p[0]=Krow[0]*va.x; p[1]=Krow[1]*va.y; p[2]=Krow[2]*va.z; p[3]=Krow[3]*va.w;
        p[4]=Krow[4]*vb.x; p[5]=Krow[5]*vb.y; p[6]=Krow[6]*vb.z; p[7]=Krow[7]*vb.w;
        float sr = red8_dpp(((p[0]+p[1])+(p[2]+p[3])) + ((p[4]+p[5])+(p[6]+p[7])));
        short8 xs;
        #pragma unroll
        for (int u = 0; u < 8; ++u) {
            float xv = uR * p[u];
            XK[rr8*65 + c8 + u] = xv;
            xs[u] = (short)f2bf(xv);
        }
        // frag chunk: row rr8, cols c8..c8+7 -> T=rr8>>4, lr=rr8&15, kc=q8>>2, lg=q8&3
        int ci = (((((rr8>>4)<<1) + (q8>>2))*4 + (q8&3))*16 + (rr8&15)) << 3;
        *(short8*)&Xb[ci] = xs;
        if (q8 == 0) rX[rr8] = uR * sr;
        __syncthreads();
    };

    // M1: P_a = X * W_a (MFMA) + eid*rX fold, write R'_a^T bf16 into Rb
    auto M1R = [&]() {
        #pragma unroll
        for (int s = 0; s < 2; ++s) {
            const int rt = rts[s], ct = cts[s];
            f32x4 P0 = {0.f,0.f,0.f,0.f}, P1 = P0, P2 = P0, P3 = P0;
            #pragma unroll
            for (int kc = 0; kc < 2; ++kc) {
                const int ai = ((((rt<<1)+kc)*4 + lg)*16 + lr) << 3;   // Xb chunk
                const int bi = ((((ct<<1)+kc)*4 + lg)*16 + lr) << 3;   // Wb chunk
                short8 af = *(const short8*)&Xb[ai];
                P0 = __builtin_amdgcn_mfma_f32_16x16x32_bf16(af, *(const short8*)&Wb[0][bi], P0, 0,0,0);
                P1 = __builtin_amdgcn_mfma_f32_16x16x32_bf16(af, *(const short8*)&Wb[1][bi], P1, 0,0,0);
                P2 = __builtin_amdgcn_mfma_f32_16x16x32_bf16(af, *(const short8*)&Wb[2][bi], P2, 0,0,0);
                P3 = __builtin_amdgcn_mfma_f32_16x16x32_bf16(af, *(const short8*)&Wb[3][bi], P3, 0,0,0);
            }
            // rank-1 fold: R'[k][j] = P[k][j] + eid*rX[k], k = i0s[s]+r (16B aligned)
            float4 rx4 = *(const float4*)&rX[i0s[s]];
            P0[0] += eid*rx4.x; P0[1] += eid*rx4.y; P0[2] += eid*rx4.z; P0[3] += eid*rx4.w;
            P1[0] += eid*rx4.x; P1[1] += eid*rx4.y; P1[2] += eid*rx4.z; P1[3] += eid*rx4.w;
            P2[0] += eid*rx4.x; P2[1] += eid*rx4.y; P2[2] += eid*rx4.z; P2[3] += eid*rx4.w;
            P3[0] += eid*rx4.x; P3[1] += eid*rx4.y; P3[2] += eid*rx4.z; P3[3] += eid*rx4.w;
            // R^T element (j = ct*16+lr, k = rt*16+lg*4+r):
            const int cw = (((ct<<1) + (rt>>1))*4 + ((rt&1)*2 + (lg>>1)))*16 + lr;
            const int si = (cw << 3) + ((lg & 1) << 2);
            {
                unsigned long long v =  (unsigned long long)(f2bf(P0[0]) | ((unsigned)f2bf(P0[1])<<16))
                                     | ((unsigned long long)(f2bf(P0[2]) | ((unsigned)f2bf(P0[3])<<16)) << 32);
                *(unsigned long long*)&Rb[0][si] = v;
            }
            {
                unsigned long long v =  (unsigned long long)(f2bf(P1[0]) | ((unsigned)f2bf(P1[1])<<16))
                                     | ((unsigned long long)(f2bf(P1[2]) | ((unsigned)f2bf(P1[3])<<16)) << 32);
                *(unsigned long long*)&Rb[1][si] = v;
            }
            {
                unsigned long long v =  (unsigned long long)(f2bf(P2[0]) | ((unsigned)f2bf(P2[1])<<16))
                                     | ((unsigned long long)(f2bf(P2[2]) | ((unsigned)f2bf(P2[3])<<16)) << 32);
                *(unsigned long long*)&Rb[2][si] = v;
            }
            {
                unsigned long long v =  (unsigned long long)(f2bf(P3[0]) | ((unsigned)f2bf(P3[1])<<16))
                                     | ((unsigned long long)(f2bf(P3[2]) | ((unsigned)f2bf(P3[3])<<16)) << 32);
                *(unsigned long long*)&Rb[3][si] = v;
            }
        }
        __syncthreads();
    };

    // M2: out = sum_a I1_a * R'_a  (+ eid*deg2), db in D-frag regs
    auto M2 = [&](float (*out)[4]) {
        #pragma unroll
        for (int s = 0; s < 2; ++s) {
            const int rt = rts[s], ct = cts[s];
            f32x4 acc = {0.f,0.f,0.f,0.f};
            #pragma unroll
            for (int kc = 0; kc < 2; ++kc) {
                const int ai = ((((rt<<1)+kc)*4 + lg)*16 + lr) << 3;   // I1 chunk
                const int bi = ((((ct<<1)+kc)*4 + lg)*16 + lr) << 3;   // Rb chunk
                #pragma unroll
                for (int a = 0; a < 4; ++a) {
                    short8 af = *(const short8*)&I1b[a][ai];
                    short8 bf = *(const short8*)&Rb[a][bi];
                    acc = __builtin_amdgcn_mfma_f32_16x16x32_bf16(af, bf, acc, 0,0,0);
                }
            }
            #pragma unroll
            for (int r = 0; r < 4; ++r) out[s][r] = acc[r] + ed2s[s];
        }
    };

    // ---- init: x0 = sinkhorn(exp(-c), 10); dx = D @ x0 ----
    expK(c_reg);
    sink8(10);
    fin8();
    M1R();
    float x[2][4], dx[2][4], bb[2][4], gvv[2][4];
    M2(dx);
    #pragma unroll
    for (int s = 0; s < 2; ++s)
        #pragma unroll
        for (int r = 0; r < 4; ++r)
            x[s][r] = XK[(i0s[s] + r)*65 + jcs[s]];

    // ---- Frank-Wolfe iterations ----
    for (int it = 0; it < 15; ++it) {
        #pragma unroll
        for (int s = 0; s < 2; ++s)
            #pragma unroll
            for (int r = 0; r < 4; ++r)
                gvv[s][r] = c_reg[s][r] + dx[s][r];
        expK(gvv);
        sink8(5);
        fin8();
        M1R();
        float db[2][4];
        M2(db);
        #pragma unroll
        for (int s = 0; s < 2; ++s)
            #pragma unroll
            for (int r = 0; r < 4; ++r)
                bb[s][r] = XK[(i0s[s] + r)*65 + jcs[s]];
        float dn = 0.f, nm = 0.f;
        #pragma unroll
        for (int s = 0; s < 2; ++s)
            #pragma unroll
            for (int r = 0; r < 4; ++r) {
                float d = bb[s][r] - x[s][r];
                dn += d * (db[s][r] - dx[s][r]);
                nm += d * gvv[s][r];
            }
        dn = red8_dpp(dn);  nm = red8_dpp(nm);       // 8-group sums on VALU
        dn += __shfl_xor(dn, 8, 64);  nm += __shfl_xor(nm, 8, 64);
        dn += __shfl_xor(dn, 16, 64); nm += __shfl_xor(nm, 16, 64);
        dn += __shfl_xor(dn, 32, 64); nm += __shfl_xor(nm, 32, 64);
        if (lane == 0) { red[w] = dn; red[8 + w] = nm; }
        __syncthreads();
        float4 pa = *(const float4*)&red[0], pb = *(const float4*)&red[4];
        float4 pc = *(const float4*)&red[8], pd = *(const float4*)&red[12];
        float den = (pa.x+pa.y+pa.z+pa.w) + (pb.x+pb.y+pb.z+pb.w);
        float num = (pc.x+pc.y+pc.z+pc.w) + (pd.x+pd.y+pd.z+pd.w);
        float t;
        if (den > 0.f) t = fminf(fmaxf(-num / den, 0.f), 1.f);
        else           t = (num < 0.f) ? 1.f : 0.f;
        #pragma unroll
        for (int s = 0; s < 2; ++s)
            #pragma unroll
            for (int r = 0; r < 4; ++r) {
                float d = bb[s][r] - x[s][r];
                x[s][r]  += t * d;
                dx[s][r] += t * (db[s][r] - dx[s][r]);   // D x_new by linearity
            }
    }

    // ---- ged = 0.5 * x.Dx + c.x ----
    __syncthreads();   // red[] reads above complete before rewrite
    float g2 = 0.f;
    #pragma unroll
    for (int s = 0; s < 2; ++s)
        #pragma unroll
        for (int r = 0; r < 4; ++r)
            g2 += x[s][r] * (0.5f * dx[s][r] + c_reg[s][r]);
    g2 = red8_dpp(g2);
    g2 += __shfl_xor(g2, 8, 64);
    g2 += __shfl_xor(g2, 16, 64);
    g2 += __shfl_xor(g2, 32, 64);
    if (lane == 0) red[w] = g2;
    __syncthreads();
    if (tid == 0) {
        float s = 0.f;
        #pragma unroll
        for (int u = 0; u < 8; ++u) s += red[u];
        ged_out[b] = s;
    }
}

__global__ void norm_kernel(const float* __restrict__ g, float* __restrict__ out) {
    int t = threadIdx.x;
    if (t < NBATCH) {
        float mn = g[0], mx = g[0];
        #pragma unroll
        for (int i = 1; i < NBATCH; ++i) { mn = fminf(mn, g[i]); mx = fmaxf(mx, g[i]); }
        out[t] = (g[t] - mn) / (mx - mn);
    }
}

extern "C" void kernel_launch(void* const* d_in, const int* in_sizes, int n_in,
                              void* d_out, int out_size, void* d_ws, size_t ws_size,
                              hipStream_t stream) {
    (void)in_sizes; (void)n_in; (void)out_size; (void)ws_size;
    const float* node_w = (const float*)d_in[0];
    const float* edge_w = (const float*)d_in[1];
    const int*   A1     = (const int*)d_in[2];
    const int*   A2     = (const int*)d_in[3];
    const int*   l1     = (const int*)d_in[4];
    const int*   l2     = (const int*)d_in[5];
    float* ged = (float*)d_ws;
    ged_kernel<<<dim3(NBATCH), dim3(512), 0, stream>>>(node_w, edge_w, A1, A2, l1, l2, ged);
    norm_kernel<<<dim3(1), dim3(64), 0, stream>>>(ged, (float*)d_out);
}